// Round 6
// baseline (397.673 us; speedup 1.0000x reference)
//
#include <hip/hip_runtime.h>

#define LTC_B 512
#define LTC_H 512
#define LTC_I 256

static constexpr float kL2E = 1.4426950408889634f;  // log2(e)

typedef unsigned int u32;
#define AS_G __attribute__((address_space(1)))
#define AS_L __attribute__((address_space(3)))

__device__ __forceinline__ void ldg_lds16(const void* g, void* l) {
    // async global->LDS DMA, 16B/lane; LDS dest = wave-uniform base + lane*16
    __builtin_amdgcn_global_load_lds((const AS_G u32*)g, (AS_L u32*)l, 16, 0, 0);
}

// f32 weight quad per (j,h): a = -sigma*log2(e), ec = 2^(mu*sigma*log2(e)),
// wz = W*erev, wd = W.  sigma(b,j,h) = 1 / (1 + ec * 2^(a*v(b,j))).
// Quad index = (ht4*K + j)*4 + hh4, h = ht4*4 + hh4: a 16-j window of one
// ht4 is a contiguous 1KB run -> exactly one global_load_lds per window.
template<int K, int LOG2K>
__global__ void ltc_prep(const float* __restrict__ mu, const float* __restrict__ sigma,
                         const float* __restrict__ W, const float* __restrict__ erev,
                         float4* __restrict__ slab) {
    const int t = blockIdx.x * 256 + threadIdx.x;   // one thread per quad
    if (t >= K * LTC_H) return;
    const int hh4  = t & 3;
    const int rest = t >> 2;
    const int j    = rest & (K - 1);
    const int ht4  = rest >> LOG2K;
    const int h    = ht4 * 4 + hh4;
    const int g    = j * LTC_H + h;
    const float sg = sigma[g];
    float4 o;
    o.x = -sg * kL2E;                    // a
    o.y = exp2f(mu[g] * sg * kL2E);      // ec = 2^c
    o.z = W[g] * erev[g];                // wz
    o.w = W[g];                          // wd
    slab[t] = o;                         // coalesced 16B/lane
}

// Transpose B x C row-major -> v4 layout [C/4][B][4] (4 consecutive k packed
// per b so the pass kernel loads one float4 per 4 j). grid (C/64, B/64).
// R5 bug fixed: read phase must take tile[tx][c] (= in(b=by+tx, k=bx+c)),
// not tile[c][tx], which permuted b<->k inside each 64x64 tile.
__global__ void ltc_transpose_v4(const float* __restrict__ in, float* __restrict__ out,
                                 int R, int C) {   // R = rows of in (= B)
    __shared__ float tile[64][65];
    const int bx = blockIdx.x * 64;      // col (k) base
    const int by = blockIdx.y * 64;      // row (b) base
    const int tx = threadIdx.x & 63;
    const int t4 = threadIdx.x >> 6;
    #pragma unroll
    for (int r = t4; r < 64; r += 4)
        tile[r][tx] = in[(size_t)(by + r) * C + bx + tx];
    __syncthreads();
    #pragma unroll
    for (int c = t4; c < 64; c += 4) {
        const int k = bx + c;
        out[((size_t)(k >> 2) * R + by + tx) * 4 + (k & 3)] = tile[tx][c];
    }
}

// Lane = BATCH, deep-pipelined. Block = 512 thr = 8 waves = 8 j-slices for
// the same (4-h tile, 64-b column). Weights stream via PER-WAVE LDS DMA
// rings (global_load_lds, 1KB/window, double-buffered, vmcnt-paced -- no
// registers consumed, no barriers in the loop, one-window (~1470 cyc)
// lookahead >> L2 latency). v streams as float4 (4 j) with one-window
// lookahead in VGPRs. Weights consumed via broadcast ds_read_b128.
// The per-window waitcnt includes lgkmcnt(0): it orders window-w ds_reads
// (long complete by then) before window-(w+2)'s DMA reuses their buffer.
// MODE: 0 = sensory (write snumT/sdenT HxB), 1 = recurrent (write vT4),
//       2 = last recurrent (write out B x H).
template<int K, int MODE>
__global__ __launch_bounds__(512, 8)
void ltc_pass(const float4* __restrict__ vT4,    // [K/4][B][4]
              const float4* __restrict__ slab,   // [128][K][4]
              const float* __restrict__ snumT, const float* __restrict__ sdenT, // H x B
              const float* __restrict__ vleak, const float* __restrict__ gleak,
              const float* __restrict__ cm,
              float* __restrict__ o0, float* __restrict__ o1)
{
    constexpr int JW = K / 8;                    // j's per wave (64 / 32)
    constexpr int NW = JW / 16;                  // 16-j windows (4 / 2)

    __shared__ float4 wbuf[8][2][64];            // 16 KB: per-wave DMA ring
    __shared__ float2 comb[8][4][64];            // 16 KB: partials

    const int tid  = threadIdx.x;
    const int lane = tid & 63;
    const int wu   = __builtin_amdgcn_readfirstlane(tid >> 6);  // j-slice
    const int ht4  = blockIdx.x;                 // 0..127
    const int b0   = blockIdx.y * 64;

    // weight source: contiguous 1KB windows for this wave's j-slice
    const char* sbase = (const char*)slab + ((size_t)ht4 * K + (size_t)wu * JW) * 64;
    // v source: float4 per 4 j, this lane's b
    const float4* __restrict__ vp4 = vT4 + (size_t)(wu * (JW / 4)) * LTC_B + b0 + lane;

    float na0 = 0.f, da0 = 0.f, na1 = 0.f, da1 = 0.f;
    float na2 = 0.f, da2 = 0.f, na3 = 0.f, da3 = 0.f;
    float4 vbuf[2][4];

    // prologue: window 0 in flight
    ldg_lds16(sbase + (size_t)lane * 16, &wbuf[wu][0][0]);
    #pragma unroll
    for (int q = 0; q < 4; ++q) vbuf[0][q] = vp4[(size_t)q * LTC_B];

    #pragma unroll
    for (int w = 0; w < NW; ++w) {
        // window w's DMA complete + window w-1's ds_reads retired (buffer safe)
        asm volatile("s_waitcnt vmcnt(0) lgkmcnt(0)" ::: "memory");
        if (w + 1 < NW) {                        // issue w+1: flies under compute w
            ldg_lds16(sbase + (w + 1) * 1024 + (size_t)lane * 16,
                      &wbuf[wu][(w + 1) & 1][0]);
            #pragma unroll
            for (int q = 0; q < 4; ++q)
                vbuf[(w + 1) & 1][q] = vp4[(size_t)((w + 1) * 4 + q) * LTC_B];
        }
        const float4* wq = &wbuf[wu][w & 1][0];
        #pragma unroll
        for (int jl = 0; jl < 16; ++jl) {
            const float4 vv = vbuf[w & 1][jl >> 2];
            const float vj = (jl & 3) == 0 ? vv.x : (jl & 3) == 1 ? vv.y
                           : (jl & 3) == 2 ? vv.z : vv.w;       // static after unroll
            const float4 q0 = wq[jl * 4 + 0];    // broadcast ds_read_b128
            const float4 q1 = wq[jl * 4 + 1];
            const float4 q2 = wq[jl * 4 + 2];
            const float4 q3 = wq[jl * 4 + 3];
            const float e0 = __builtin_amdgcn_exp2f(q0.x * vj);
            const float e1 = __builtin_amdgcn_exp2f(q1.x * vj);
            const float e2 = __builtin_amdgcn_exp2f(q2.x * vj);
            const float e3 = __builtin_amdgcn_exp2f(q3.x * vj);
            const float d0 = fmaf(q0.y, e0, 1.0f);
            const float d1 = fmaf(q1.y, e1, 1.0f);
            const float d2 = fmaf(q2.y, e2, 1.0f);
            const float d3 = fmaf(q3.y, e3, 1.0f);
            const float r01 = __builtin_amdgcn_rcpf(d0 * d1);   // 1 rcp / 2 sigmoids
            const float r23 = __builtin_amdgcn_rcpf(d2 * d3);
            const float s0 = r01 * d1, s1 = r01 * d0;
            const float s2 = r23 * d3, s3 = r23 * d2;
            na0 = fmaf(q0.z, s0, na0); da0 = fmaf(q0.w, s0, da0);
            na1 = fmaf(q1.z, s1, na1); da1 = fmaf(q1.w, s1, da1);
            na2 = fmaf(q2.z, s2, na2); da2 = fmaf(q2.w, s2, da2);
            na3 = fmaf(q3.z, s3, na3); da3 = fmaf(q3.w, s3, da3);
        }
    }

    comb[wu][0][lane] = make_float2(na0, da0);
    comb[wu][1][lane] = make_float2(na1, da1);
    comb[wu][2][lane] = make_float2(na2, da2);
    comb[wu][3][lane] = make_float2(na3, da3);
    __syncthreads();

    if (wu < 4) {                                // wave wu finishes h = ht4*4+wu
        float na = 0.f, da = 0.f;
        #pragma unroll
        for (int js = 0; js < 8; ++js) {
            const float2 p = comb[js][wu][lane];
            na += p.x; da += p.y;
        }
        const int h = ht4 * 4 + wu;
        const int b = b0 + lane;
        if constexpr (MODE == 0) {
            const size_t hb = (size_t)h * LTC_B + b;
            o0[hb] = na;                         // snumT (coalesced)
            o1[hb] = da;                         // sdenT
        } else {
            const size_t hb = (size_t)h * LTC_B + b;
            const size_t v4i = ((size_t)ht4 * LTC_B + b) * 4 + wu;  // vT4 slot of (h,b)
            const float gl = gleak[h], vl = vleak[h], c0 = cm[h];
            const float vpre = ((const float*)vT4)[v4i];            // K==H here
            const float num = fmaf(c0, vpre, gl * vl) + na + snumT[hb];
            const float den = c0 + gl + da + sdenT[hb];
            const float vn = num * __builtin_amdgcn_rcpf(den + 1e-8f);
            if constexpr (MODE == 1) o0[v4i] = vn;          // next vT4
            else o0[(size_t)b * LTC_H + h] = vn;            // final B x H
        }
    }
}

extern "C" void kernel_launch(void* const* d_in, const int* in_sizes, int n_in,
                              void* d_out, int out_size, void* d_ws, size_t ws_size,
                              hipStream_t stream) {
    const float* inputs = (const float*)d_in[0];   // B x I
    const float* state  = (const float*)d_in[1];   // B x H
    const float* smu    = (const float*)d_in[2];   // I x H
    const float* ssig   = (const float*)d_in[3];
    const float* sW     = (const float*)d_in[4];
    const float* serev  = (const float*)d_in[5];
    const float* mu     = (const float*)d_in[6];   // H x H
    const float* sig    = (const float*)d_in[7];
    const float* W      = (const float*)d_in[8];
    const float* erev   = (const float*)d_in[9];
    const float* vleak  = (const float*)d_in[10];  // H
    const float* gleak  = (const float*)d_in[11];
    const float* cm     = (const float*)d_in[12];

    float* out = (float*)d_out;                    // B x H
    char*  ws  = (char*)d_ws;
    float*  snumT = (float*)(ws);                            // 1MB  H x B
    float*  sdenT = (float*)(ws + 1 * 1048576);              // 1MB  H x B
    float4* vA    = (float4*)(ws + 2 * 1048576);             // 1MB  [H/4][B][4]
    float4* vB    = (float4*)(ws + 3 * 1048576);             // 1MB  [H/4][B][4]
    float4* rslab = (float4*)(ws + 4 * 1048576);             // 4MB  [128][512][4]
    float4* sslab = (float4*)(ws + 8 * 1048576);             // 2MB  [128][256][4]
    float4* inpT4 = (float4*)(ws + 10 * 1048576);            // 0.5MB [I/4][B][4]

    // Weight transform (f32 quads, once per launch). One thread per (j,h).
    ltc_prep<LTC_H, 9><<<LTC_H * LTC_H / 256, 256, 0, stream>>>(mu, sig, W, erev, rslab);
    ltc_prep<LTC_I, 8><<<LTC_I * LTC_H / 256, 256, 0, stream>>>(smu, ssig, sW, serev, sslab);

    // Activations into v4 layout.
    ltc_transpose_v4<<<dim3(LTC_I / 64, LTC_B / 64), 256, 0, stream>>>(inputs, (float*)inpT4, LTC_B, LTC_I);
    ltc_transpose_v4<<<dim3(LTC_H / 64, LTC_B / 64), 256, 0, stream>>>(state, (float*)vA, LTC_B, LTC_H);

    dim3 grid(LTC_H / 4, LTC_B / 64);              // (128 h-tiles, 8 b-cols)
    dim3 blk(512);

    // Sensory pass -> snumT/sdenT (H x B).
    ltc_pass<LTC_I, 0><<<grid, blk, 0, stream>>>(
        inpT4, sslab, nullptr, nullptr, nullptr, nullptr, nullptr,
        (float*)snumT, (float*)sdenT);

    // 6 unfolds: vA -> vB -> ... ; last writes B x H into d_out.
    const float4* vin = vA;
    float4* vping[5] = {vB, vA, vB, vA, vB};
    for (int s = 0; s < 5; ++s) {
        ltc_pass<LTC_H, 1><<<grid, blk, 0, stream>>>(
            vin, rslab, snumT, sdenT, vleak, gleak, cm, (float*)vping[s], nullptr);
        vin = vping[s];
    }
    ltc_pass<LTC_H, 2><<<grid, blk, 0, stream>>>(
        vin, rslab, snumT, sdenT, vleak, gleak, cm, out, nullptr);
}

// Round 7
// 397.604 us; speedup vs baseline: 1.0002x; 1.0002x over previous
//
#include <hip/hip_runtime.h>

#define LTC_B 512
#define LTC_H 512
#define LTC_I 256

static constexpr float kL2E = 1.4426950408889634f;  // log2(e)

// f32 weight quad per (j,h): a = -sigma*log2(e), ec = 2^(mu*sigma*log2(e)),
// wz = W*erev, wd = W.  sigma(b,j,h) = 1 / (1 + ec * 2^(a*v(b,j))).
// Quad index = (ht4*K + j)*4 + hh4, h = ht4*4 + hh4: the 4 h's of one (ht4,j)
// are one 64B group -> a single s_load_dwordx16 per j on the scalar pipe.
template<int K, int LOG2K>
__global__ void ltc_prep(const float* __restrict__ mu, const float* __restrict__ sigma,
                         const float* __restrict__ W, const float* __restrict__ erev,
                         float4* __restrict__ slab) {
    const int t = blockIdx.x * 256 + threadIdx.x;   // one thread per quad
    if (t >= K * LTC_H) return;
    const int hh4  = t & 3;
    const int rest = t >> 2;
    const int j    = rest & (K - 1);
    const int ht4  = rest >> LOG2K;
    const int h    = ht4 * 4 + hh4;
    const int g    = j * LTC_H + h;
    const float sg = sigma[g];
    float4 o;
    o.x = -sg * kL2E;                    // a
    o.y = exp2f(mu[g] * sg * kL2E);      // ec = 2^c
    o.z = W[g] * erev[g];                // wz
    o.w = W[g];                          // wd
    slab[t] = o;                         // coalesced 16B/lane
}

// Transpose B x C row-major -> v4 layout [C/4][B][4] (4 consecutive k packed
// per b so the pass kernel loads one float4 per 4 j). grid (C/64, B/64).
__global__ void ltc_transpose_v4(const float* __restrict__ in, float* __restrict__ out,
                                 int R, int C) {   // R = rows of in (= B)
    __shared__ float tile[64][65];
    const int bx = blockIdx.x * 64;      // col (k) base
    const int by = blockIdx.y * 64;      // row (b) base
    const int tx = threadIdx.x & 63;
    const int t4 = threadIdx.x >> 6;
    #pragma unroll
    for (int r = t4; r < 64; r += 4)
        tile[r][tx] = in[(size_t)(by + r) * C + bx + tx];
    __syncthreads();
    #pragma unroll
    for (int c = t4; c < 64; c += 4) {
        const int k = bx + c;
        out[((size_t)(k >> 2) * R + by + tx) * 4 + (k & 3)] = tile[tx][c];
    }
}

// Lane = BATCH, scalar-weight (R4 structure) + deep v pipeline + XCD locality.
// Block = 512 thr = 8 waves = 8 j-slices for one (4-h tile, 64-b column).
// Weights are wave-uniform float4 loads -> s_load on the scalar pipe (no LDS,
// no barriers in the loop, no VGPR cost). v streams as float4 (4 j each) in a
// 2-deep NAMED-REGISTER pipeline (no arrays -> no scratch; ~8 groups = ~400cy
// lookahead > L2 latency). 1D grid with XCD-aware mapping: each XCD owns 16
// contiguous ht4 tiles (512KB slab slice stays L2-resident; bcol fastest).
// MODE: 0 = sensory (write snumT/sdenT HxB), 1 = recurrent (write vT4),
//       2 = last recurrent (write out B x H).
template<int K, int MODE>
__global__ __launch_bounds__(512, 8)
void ltc_pass(const float4* __restrict__ vT4,    // [K/4][B][4]
              const float4* __restrict__ slab,   // [128][K][4]
              const float* __restrict__ snumT, const float* __restrict__ sdenT, // H x B
              const float* __restrict__ vleak, const float* __restrict__ gleak,
              const float* __restrict__ cm,
              float* __restrict__ o0, float* __restrict__ o1)
{
    constexpr int JW = K / 8;                    // j's per wave (64 / 32)
    constexpr int NG = JW / 4;                   // float4 v-groups (16 / 8)

    __shared__ float2 comb[8][4][64];            // 16 KB partials

    const int tid  = threadIdx.x;
    const int lane = tid & 63;
    const int wu   = __builtin_amdgcn_readfirstlane(tid >> 6);  // j-slice

    // XCD-aware block mapping: xcd = bid & 7 (round-robin dispatch); each XCD
    // covers ht4 in [xcd*16, xcd*16+16) for all 8 b-columns.
    const int bid = blockIdx.x;                  // 0..1023
    const int g8  = bid >> 3;                    // 0..127
    const int ht4 = (bid & 7) * 16 + (g8 & 15);  // 16 ht4 per XCD
    const int b0  = (g8 >> 4) * 64;              // b-column

    const float4* __restrict__ wq  = slab + ((size_t)ht4 * K + (size_t)wu * JW) * 4;
    const float4* __restrict__ vp4 = vT4 + (size_t)(wu * NG) * LTC_B + b0 + lane;

    float na0 = 0.f, da0 = 0.f, na1 = 0.f, da1 = 0.f;
    float na2 = 0.f, da2 = 0.f, na3 = 0.f, da3 = 0.f;

    // one v-group = 4 j's x 4 h's (16 wave-uniform quads via s_load)
    auto grp = [&](const float4 u, const int g) {
        #pragma unroll
        for (int t = 0; t < 4; ++t) {
            const float vj = t == 0 ? u.x : t == 1 ? u.y : t == 2 ? u.z : u.w;
            const int j = g * 4 + t;
            const float4 q0 = wq[j * 4 + 0];
            const float4 q1 = wq[j * 4 + 1];
            const float4 q2 = wq[j * 4 + 2];
            const float4 q3 = wq[j * 4 + 3];
            const float e0 = __builtin_amdgcn_exp2f(q0.x * vj);
            const float e1 = __builtin_amdgcn_exp2f(q1.x * vj);
            const float e2 = __builtin_amdgcn_exp2f(q2.x * vj);
            const float e3 = __builtin_amdgcn_exp2f(q3.x * vj);
            const float d0 = fmaf(q0.y, e0, 1.0f);
            const float d1 = fmaf(q1.y, e1, 1.0f);
            const float d2 = fmaf(q2.y, e2, 1.0f);
            const float d3 = fmaf(q3.y, e3, 1.0f);
            const float r01 = __builtin_amdgcn_rcpf(d0 * d1);   // 1 rcp / 2 sigmoids
            const float r23 = __builtin_amdgcn_rcpf(d2 * d3);
            const float s0 = r01 * d1, s1 = r01 * d0;
            const float s2 = r23 * d3, s3 = r23 * d2;
            na0 = fmaf(q0.z, s0, na0); da0 = fmaf(q0.w, s0, da0);
            na1 = fmaf(q1.z, s1, na1); da1 = fmaf(q1.w, s1, da1);
            na2 = fmaf(q2.z, s2, na2); da2 = fmaf(q2.w, s2, da2);
            na3 = fmaf(q3.z, s3, na3); da3 = fmaf(q3.w, s3, da3);
        }
    };

    // 2-deep named-register v pipeline: load g+2/g+3 while computing g/g+1.
    float4 vA = vp4[0];
    float4 vB = vp4[LTC_B];
    #pragma unroll 2
    for (int g = 0; g < NG; g += 2) {
        const float4 u0 = vA;
        if (g + 2 < NG) vA = vp4[(size_t)(g + 2) * LTC_B];
        grp(u0, g);
        const float4 u1 = vB;
        if (g + 3 < NG) vB = vp4[(size_t)(g + 3) * LTC_B];
        grp(u1, g + 1);
    }

    comb[wu][0][lane] = make_float2(na0, da0);
    comb[wu][1][lane] = make_float2(na1, da1);
    comb[wu][2][lane] = make_float2(na2, da2);
    comb[wu][3][lane] = make_float2(na3, da3);
    __syncthreads();

    if (wu < 4) {                                // wave wu finishes h = ht4*4+wu
        float na = 0.f, da = 0.f;
        #pragma unroll
        for (int js = 0; js < 8; ++js) {
            const float2 p = comb[js][wu][lane];
            na += p.x; da += p.y;
        }
        const int h = ht4 * 4 + wu;
        const int b = b0 + lane;
        if constexpr (MODE == 0) {
            const size_t hb = (size_t)h * LTC_B + b;
            o0[hb] = na;                         // snumT (coalesced)
            o1[hb] = da;                         // sdenT
        } else {
            const size_t hb = (size_t)h * LTC_B + b;
            const size_t v4i = ((size_t)ht4 * LTC_B + b) * 4 + wu;  // vT4 slot of (h,b)
            const float gl = gleak[h], vl = vleak[h], c0 = cm[h];
            const float vpre = ((const float*)vT4)[v4i];            // K==H here
            const float num = fmaf(c0, vpre, gl * vl) + na + snumT[hb];
            const float den = c0 + gl + da + sdenT[hb];
            const float vn = num * __builtin_amdgcn_rcpf(den + 1e-8f);
            if constexpr (MODE == 1) o0[v4i] = vn;          // next vT4
            else o0[(size_t)b * LTC_H + h] = vn;            // final B x H
        }
    }
}

extern "C" void kernel_launch(void* const* d_in, const int* in_sizes, int n_in,
                              void* d_out, int out_size, void* d_ws, size_t ws_size,
                              hipStream_t stream) {
    const float* inputs = (const float*)d_in[0];   // B x I
    const float* state  = (const float*)d_in[1];   // B x H
    const float* smu    = (const float*)d_in[2];   // I x H
    const float* ssig   = (const float*)d_in[3];
    const float* sW     = (const float*)d_in[4];
    const float* serev  = (const float*)d_in[5];
    const float* mu     = (const float*)d_in[6];   // H x H
    const float* sig    = (const float*)d_in[7];
    const float* W      = (const float*)d_in[8];
    const float* erev   = (const float*)d_in[9];
    const float* vleak  = (const float*)d_in[10];  // H
    const float* gleak  = (const float*)d_in[11];
    const float* cm     = (const float*)d_in[12];

    float* out = (float*)d_out;                    // B x H
    char*  ws  = (char*)d_ws;
    float*  snumT = (float*)(ws);                            // 1MB  H x B
    float*  sdenT = (float*)(ws + 1 * 1048576);              // 1MB  H x B
    float4* vA    = (float4*)(ws + 2 * 1048576);             // 1MB  [H/4][B][4]
    float4* vB    = (float4*)(ws + 3 * 1048576);             // 1MB  [H/4][B][4]
    float4* rslab = (float4*)(ws + 4 * 1048576);             // 4MB  [128][512][4]
    float4* sslab = (float4*)(ws + 8 * 1048576);             // 2MB  [128][256][4]
    float4* inpT4 = (float4*)(ws + 10 * 1048576);            // 0.5MB [I/4][B][4]

    // Weight transform (f32 quads, once per launch). One thread per (j,h).
    ltc_prep<LTC_H, 9><<<LTC_H * LTC_H / 256, 256, 0, stream>>>(mu, sig, W, erev, rslab);
    ltc_prep<LTC_I, 8><<<LTC_I * LTC_H / 256, 256, 0, stream>>>(smu, ssig, sW, serev, sslab);

    // Activations into v4 layout.
    ltc_transpose_v4<<<dim3(LTC_I / 64, LTC_B / 64), 256, 0, stream>>>(inputs, (float*)inpT4, LTC_B, LTC_I);
    ltc_transpose_v4<<<dim3(LTC_H / 64, LTC_B / 64), 256, 0, stream>>>(state, (float*)vA, LTC_B, LTC_H);

    dim3 grid(1024);                               // 1D: XCD-aware mapping inside
    dim3 blk(512);

    // Sensory pass -> snumT/sdenT (H x B).
    ltc_pass<LTC_I, 0><<<grid, blk, 0, stream>>>(
        inpT4, sslab, nullptr, nullptr, nullptr, nullptr, nullptr,
        (float*)snumT, (float*)sdenT);

    // 6 unfolds: vA -> vB -> ... ; last writes B x H into d_out.
    const float4* vin = vA;
    float4* vping[5] = {vB, vA, vB, vA, vB};
    for (int s = 0; s < 5; ++s) {
        ltc_pass<LTC_H, 1><<<grid, blk, 0, stream>>>(
            vin, rslab, snumT, sdenT, vleak, gleak, cm, (float*)vping[s], nullptr);
        vin = vping[s];
    }
    ltc_pass<LTC_H, 2><<<grid, blk, 0, stream>>>(
        vin, rslab, snumT, sdenT, vleak, gleak, cm, out, nullptr);
}

// Round 8
// 312.437 us; speedup vs baseline: 1.2728x; 1.2726x over previous
//
#include <hip/hip_runtime.h>

#define LTC_B 512
#define LTC_H 512
#define LTC_I 256

typedef float v2f __attribute__((ext_vector_type(2)));
static constexpr float kL2E = 1.4426950408889634f;  // log2(e)

// f32 weight quad per (j,h): a = -sigma*log2(e), ec = 2^(mu*sigma*log2(e)),
// wz = W*erev, wd = W.  sigma(b,j,h) = 1 / (1 + ec * 2^(a*v(b,j))).
// Quad index = (ht4*K + j)*4 + hh4, h = ht4*4 + hh4. Viewed as v2f pairs:
// (a,ec) then (wz,wd) -- the (wz,wd) pair lands in an even-aligned SGPR pair
// so the accumulation can be a single v_pk_fma_f32.
template<int K, int LOG2K>
__global__ void ltc_prep(const float* __restrict__ mu, const float* __restrict__ sigma,
                         const float* __restrict__ W, const float* __restrict__ erev,
                         float4* __restrict__ slab) {
    const int t = blockIdx.x * 256 + threadIdx.x;   // one thread per quad
    if (t >= K * LTC_H) return;
    const int hh4  = t & 3;
    const int rest = t >> 2;
    const int j    = rest & (K - 1);
    const int ht4  = rest >> LOG2K;
    const int h    = ht4 * 4 + hh4;
    const int g    = j * LTC_H + h;
    const float sg = sigma[g];
    float4 o;
    o.x = -sg * kL2E;                    // a
    o.y = exp2f(mu[g] * sg * kL2E);      // ec = 2^c
    o.z = W[g] * erev[g];                // wz
    o.w = W[g];                          // wd
    slab[t] = o;                         // coalesced 16B/lane
}

// Transpose B x C row-major -> v4 layout [C/4][B][4] (4 consecutive k packed
// per b so the pass kernel loads one float4 per 4 j). grid (C/64, B/64).
__global__ void ltc_transpose_v4(const float* __restrict__ in, float* __restrict__ out,
                                 int R, int C) {   // R = rows of in (= B)
    __shared__ float tile[64][65];
    const int bx = blockIdx.x * 64;      // col (k) base
    const int by = blockIdx.y * 64;      // row (b) base
    const int tx = threadIdx.x & 63;
    const int t4 = threadIdx.x >> 6;
    #pragma unroll
    for (int r = t4; r < 64; r += 4)
        tile[r][tx] = in[(size_t)(by + r) * C + bx + tx];
    __syncthreads();
    #pragma unroll
    for (int c = t4; c < 64; c += 4) {
        const int k = bx + c;
        out[((size_t)(k >> 2) * R + by + tx) * 4 + (k & 3)] = tile[tx][c];
    }
}

// Lane = BATCH, scalar-SGPR weights (R4 structure), arithmetic-optimized:
// 4-way rcp batching (0.25 rcp/eval) + packed (na,da) v_pk_fma accumulation.
// Block = 512 thr = 8 waves = 8 j-slices for one (4-h tile, 64-b column).
// Weights are wave-uniform v2f loads -> s_load on the scalar pipe. v streams
// as float4 (4 j) with 2-deep named-register lookahead. Compact 4-j loop
// body (16 hw iterations), no barriers in the main loop. 2D grid as in R4.
// MODE: 0 = sensory (write snumT/sdenT HxB), 1 = recurrent (write vT4),
//       2 = last recurrent (write out B x H).
template<int K, int MODE>
__global__ __launch_bounds__(512, 8)
void ltc_pass(const float4* __restrict__ vT4,    // [K/4][B][4]
              const v2f* __restrict__ slab2,     // [128][K][4][2] v2f view
              const float* __restrict__ snumT, const float* __restrict__ sdenT, // H x B
              const float* __restrict__ vleak, const float* __restrict__ gleak,
              const float* __restrict__ cm,
              float* __restrict__ o0, float* __restrict__ o1)
{
    constexpr int JW = K / 8;                    // j's per wave (64 / 32)
    constexpr int NG = JW / 4;                   // float4 v-groups (16 / 8)

    __shared__ v2f comb[8][4][64];               // 16 KB partials (na,da)

    const int tid  = threadIdx.x;
    const int lane = tid & 63;
    const int wu   = __builtin_amdgcn_readfirstlane(tid >> 6);  // j-slice
    const int ht4  = blockIdx.x;                 // 0..127
    const int b0   = blockIdx.y * 64;

    // wave's weight slice: 8 v2f per j
    const v2f* __restrict__ wb =
        slab2 + ((size_t)ht4 * K + (size_t)wu * JW) * 8;
    const float4* __restrict__ vp4 = vT4 + (size_t)(wu * NG) * LTC_B + b0 + lane;

    v2f acc0 = {0.f, 0.f}, acc1 = {0.f, 0.f}, acc2 = {0.f, 0.f}, acc3 = {0.f, 0.f};

    // 2-deep named-register v pipeline (no arrays -> no scratch)
    float4 va = vp4[0];
    float4 vb = vp4[LTC_B];

    #pragma unroll 1                             // compact body: 4 j per iter
    for (int g = 0; g < NG; ++g) {
        const float4 u = va;
        va = vb;
        if (g + 2 < NG) vb = vp4[(size_t)(g + 2) * LTC_B];
        const v2f* wg = wb + (size_t)g * 32;     // 4 j x 4 h x 2 v2f
        #pragma unroll
        for (int t = 0; t < 4; ++t) {
            const float vj = t == 0 ? u.x : t == 1 ? u.y : t == 2 ? u.z : u.w;
            const v2f ae0 = wg[t * 8 + 0], wz0 = wg[t * 8 + 1];
            const v2f ae1 = wg[t * 8 + 2], wz1 = wg[t * 8 + 3];
            const v2f ae2 = wg[t * 8 + 4], wz2 = wg[t * 8 + 5];
            const v2f ae3 = wg[t * 8 + 6], wz3 = wg[t * 8 + 7];
            const float e0 = __builtin_amdgcn_exp2f(ae0.x * vj);
            const float e1 = __builtin_amdgcn_exp2f(ae1.x * vj);
            const float e2 = __builtin_amdgcn_exp2f(ae2.x * vj);
            const float e3 = __builtin_amdgcn_exp2f(ae3.x * vj);
            const float d0 = fmaf(ae0.y, e0, 1.0f);
            const float d1 = fmaf(ae1.y, e1, 1.0f);
            const float d2 = fmaf(ae2.y, e2, 1.0f);
            const float d3 = fmaf(ae3.y, e3, 1.0f);
            const float p01 = d0 * d1, p23 = d2 * d3;
            const float r = __builtin_amdgcn_rcpf(p01 * p23);   // 1 rcp / 4 sigmoids
            const float rp23 = r * p23, rp01 = r * p01;
            const float s0 = rp23 * d1, s1 = rp23 * d0;
            const float s2 = rp01 * d3, s3 = rp01 * d2;
            const v2f ss0 = {s0, s0}, ss1 = {s1, s1};
            const v2f ss2 = {s2, s2}, ss3 = {s3, s3};
            acc0 = __builtin_elementwise_fma(wz0, ss0, acc0);   // v_pk_fma_f32
            acc1 = __builtin_elementwise_fma(wz1, ss1, acc1);
            acc2 = __builtin_elementwise_fma(wz2, ss2, acc2);
            acc3 = __builtin_elementwise_fma(wz3, ss3, acc3);
        }
    }

    comb[wu][0][lane] = acc0;
    comb[wu][1][lane] = acc1;
    comb[wu][2][lane] = acc2;
    comb[wu][3][lane] = acc3;
    __syncthreads();

    if (wu < 4) {                                // wave wu finishes h = ht4*4+wu
        float na = 0.f, da = 0.f;
        #pragma unroll
        for (int js = 0; js < 8; ++js) {
            const v2f p = comb[js][wu][lane];
            na += p.x; da += p.y;
        }
        const int h = ht4 * 4 + wu;
        const int b = b0 + lane;
        if constexpr (MODE == 0) {
            const size_t hb = (size_t)h * LTC_B + b;
            o0[hb] = na;                         // snumT (coalesced)
            o1[hb] = da;                         // sdenT
        } else {
            const size_t hb = (size_t)h * LTC_B + b;
            const size_t v4i = ((size_t)ht4 * LTC_B + b) * 4 + wu;  // vT4 slot of (h,b)
            const float gl = gleak[h], vl = vleak[h], c0 = cm[h];
            const float vpre = ((const float*)vT4)[v4i];            // K==H here
            const float num = fmaf(c0, vpre, gl * vl) + na + snumT[hb];
            const float den = c0 + gl + da + sdenT[hb];
            const float vn = num * __builtin_amdgcn_rcpf(den + 1e-8f);
            if constexpr (MODE == 1) o0[v4i] = vn;          // next vT4
            else o0[(size_t)b * LTC_H + h] = vn;            // final B x H
        }
    }
}

extern "C" void kernel_launch(void* const* d_in, const int* in_sizes, int n_in,
                              void* d_out, int out_size, void* d_ws, size_t ws_size,
                              hipStream_t stream) {
    const float* inputs = (const float*)d_in[0];   // B x I
    const float* state  = (const float*)d_in[1];   // B x H
    const float* smu    = (const float*)d_in[2];   // I x H
    const float* ssig   = (const float*)d_in[3];
    const float* sW     = (const float*)d_in[4];
    const float* serev  = (const float*)d_in[5];
    const float* mu     = (const float*)d_in[6];   // H x H
    const float* sig    = (const float*)d_in[7];
    const float* W      = (const float*)d_in[8];
    const float* erev   = (const float*)d_in[9];
    const float* vleak  = (const float*)d_in[10];  // H
    const float* gleak  = (const float*)d_in[11];
    const float* cm     = (const float*)d_in[12];

    float* out = (float*)d_out;                    // B x H
    char*  ws  = (char*)d_ws;
    float*  snumT = (float*)(ws);                            // 1MB  H x B
    float*  sdenT = (float*)(ws + 1 * 1048576);              // 1MB  H x B
    float4* vA    = (float4*)(ws + 2 * 1048576);             // 1MB  [H/4][B][4]
    float4* vB    = (float4*)(ws + 3 * 1048576);             // 1MB  [H/4][B][4]
    float4* rslab = (float4*)(ws + 4 * 1048576);             // 4MB  [128][512][4]
    float4* sslab = (float4*)(ws + 8 * 1048576);             // 2MB  [128][256][4]
    float4* inpT4 = (float4*)(ws + 10 * 1048576);            // 0.5MB [I/4][B][4]

    // Weight transform (f32 quads, once per launch). One thread per (j,h).
    ltc_prep<LTC_H, 9><<<LTC_H * LTC_H / 256, 256, 0, stream>>>(mu, sig, W, erev, rslab);
    ltc_prep<LTC_I, 8><<<LTC_I * LTC_H / 256, 256, 0, stream>>>(smu, ssig, sW, serev, sslab);

    // Activations into v4 layout.
    ltc_transpose_v4<<<dim3(LTC_I / 64, LTC_B / 64), 256, 0, stream>>>(inputs, (float*)inpT4, LTC_B, LTC_I);
    ltc_transpose_v4<<<dim3(LTC_H / 64, LTC_B / 64), 256, 0, stream>>>(state, (float*)vA, LTC_B, LTC_H);

    dim3 grid(LTC_H / 4, LTC_B / 64);              // (128 h-tiles, 8 b-cols) 2D
    dim3 blk(512);

    // Sensory pass -> snumT/sdenT (H x B).
    ltc_pass<LTC_I, 0><<<grid, blk, 0, stream>>>(
        inpT4, (const v2f*)sslab, nullptr, nullptr, nullptr, nullptr, nullptr,
        (float*)snumT, (float*)sdenT);

    // 6 unfolds: vA -> vB -> ... ; last writes B x H into d_out.
    const float4* vin = vA;
    float4* vping[5] = {vB, vA, vB, vA, vB};
    for (int s = 0; s < 5; ++s) {
        ltc_pass<LTC_H, 1><<<grid, blk, 0, stream>>>(
            vin, (const v2f*)rslab, snumT, sdenT, vleak, gleak, cm,
            (float*)vping[s], nullptr);
        vin = vping[s];
    }
    ltc_pass<LTC_H, 2><<<grid, blk, 0, stream>>>(
        vin, (const v2f*)rslab, snumT, sdenT, vleak, gleak, cm, out, nullptr);
}

// Round 9
// 303.619 us; speedup vs baseline: 1.3098x; 1.0290x over previous
//
#include <hip/hip_runtime.h>

#define LTC_B 512
#define LTC_H 512
#define LTC_I 256

typedef float v2f __attribute__((ext_vector_type(2)));
static constexpr float kL2E = 1.4426950408889634f;  // log2(e)

// f32 weight quad per (j,h): a = -sigma*log2(e), ec = 2^(mu*sigma*log2(e)),
// wz = W*erev, wd = W.  sigma(b,j,h) = 1 / (1 + ec * 2^(a*v(b,j))).
// Quad index = (ht4*K + j)*4 + hh4, h = ht4*4 + hh4: the 4 h's of one (ht4,j)
// are one contiguous 64B group -> batched s_load_dwordx16 on the scalar pipe.
// Viewed as v2f pairs: (a,ec) then (wz,wd); (wz,wd) lands in an aligned SGPR
// pair so the accumulation is a single v_pk_fma_f32.
template<int K, int LOG2K>
__global__ void ltc_prep(const float* __restrict__ mu, const float* __restrict__ sigma,
                         const float* __restrict__ W, const float* __restrict__ erev,
                         float4* __restrict__ slab) {
    const int t = blockIdx.x * 256 + threadIdx.x;   // one thread per quad
    if (t >= K * LTC_H) return;
    const int hh4  = t & 3;
    const int rest = t >> 2;
    const int j    = rest & (K - 1);
    const int ht4  = rest >> LOG2K;
    const int h    = ht4 * 4 + hh4;
    const int g    = j * LTC_H + h;
    const float sg = sigma[g];
    float4 o;
    o.x = -sg * kL2E;                    // a
    o.y = exp2f(mu[g] * sg * kL2E);      // ec = 2^c
    o.z = W[g] * erev[g];                // wz
    o.w = W[g];                          // wd
    slab[t] = o;                         // coalesced 16B/lane
}

// 64x64 LDS tile transpose: in R x C row-major -> out C x R. grid (C/64, R/64).
__global__ void ltc_transpose(const float* __restrict__ in, float* __restrict__ out,
                              int R, int C) {
    __shared__ float tile[64][65];
    const int bx = blockIdx.x * 64;      // col base
    const int by = blockIdx.y * 64;      // row base
    const int tx = threadIdx.x & 63;
    const int t4 = threadIdx.x >> 6;
    #pragma unroll
    for (int r = t4; r < 64; r += 4)
        tile[r][tx] = in[(size_t)(by + r) * C + bx + tx];
    __syncthreads();
    #pragma unroll
    for (int r = t4; r < 64; r += 4)
        out[(size_t)(bx + r) * R + by + tx] = tile[tx][r];
}

// Lane = BATCH, scalar-SGPR weights -- Round-4 structure EXACTLY (flat
// #pragma unroll 4 loop over all JW j's, per-lane 4B v loads, no hand
// pipeline: the compiler batches s_loads/v-loads best in this shape).
// Only change vs the 291.5us best: 4-way rcp batching (0.25 rcp/eval) and
// packed (na,da) v_pk_fma accumulation (1 fma instr instead of 2).
// Block = 512 thr = 8 waves = 8 j-slices for one (4-h tile, 64-b column).
// MODE: 0 = sensory (write snumT/sdenT HxB), 1 = recurrent (write vT KxB),
//       2 = last recurrent (write out B x H).
template<int K, int MODE>
__global__ __launch_bounds__(512, 8)
void ltc_pass(const float* __restrict__ vT,      // K x B (transposed)
              const v2f* __restrict__ slab2,     // v2f view of [128][K][4] quads
              const float* __restrict__ snumT, const float* __restrict__ sdenT, // H x B
              const float* __restrict__ vleak, const float* __restrict__ gleak,
              const float* __restrict__ cm,
              float* __restrict__ o0, float* __restrict__ o1)
{
    constexpr int JW = K / 8;                    // j's per wave (64 / 32)

    __shared__ v2f comb[8][4][64];               // 16 KB partials (na,da)

    const int tid  = threadIdx.x;
    const int lane = tid & 63;
    const int wu   = __builtin_amdgcn_readfirstlane(tid >> 6);  // j-slice
    const int ht4  = blockIdx.x;                 // 0..127
    const int b0   = blockIdx.y * 64;

    // wave's weight slice: 8 v2f per j (4 h x (a,ec)+(wz,wd))
    const v2f* __restrict__ wb = slab2 + ((size_t)ht4 * K + (size_t)wu * JW) * 8;
    // per-lane v: coalesced 4B loads, one per j
    const float* __restrict__ vp = vT + (size_t)(wu * JW) * LTC_B + b0 + lane;

    v2f acc0 = {0.f, 0.f}, acc1 = {0.f, 0.f}, acc2 = {0.f, 0.f}, acc3 = {0.f, 0.f};

    #pragma unroll 4
    for (int jj = 0; jj < JW; ++jj) {
        const float vj = vp[(size_t)jj * LTC_B];
        const v2f* wg = wb + (size_t)jj * 8;     // wave-uniform -> s_load
        const v2f ae0 = wg[0], wz0 = wg[1];
        const v2f ae1 = wg[2], wz1 = wg[3];
        const v2f ae2 = wg[4], wz2 = wg[5];
        const v2f ae3 = wg[6], wz3 = wg[7];
        const float e0 = __builtin_amdgcn_exp2f(ae0.x * vj);
        const float e1 = __builtin_amdgcn_exp2f(ae1.x * vj);
        const float e2 = __builtin_amdgcn_exp2f(ae2.x * vj);
        const float e3 = __builtin_amdgcn_exp2f(ae3.x * vj);
        const float d0 = fmaf(ae0.y, e0, 1.0f);
        const float d1 = fmaf(ae1.y, e1, 1.0f);
        const float d2 = fmaf(ae2.y, e2, 1.0f);
        const float d3 = fmaf(ae3.y, e3, 1.0f);
        const float p01 = d0 * d1, p23 = d2 * d3;
        const float r = __builtin_amdgcn_rcpf(p01 * p23);   // 1 rcp / 4 sigmoids
        const float rp23 = r * p23, rp01 = r * p01;
        const float s0 = rp23 * d1, s1 = rp23 * d0;
        const float s2 = rp01 * d3, s3 = rp01 * d2;
        const v2f ss0 = {s0, s0}, ss1 = {s1, s1};
        const v2f ss2 = {s2, s2}, ss3 = {s3, s3};
        acc0 = __builtin_elementwise_fma(wz0, ss0, acc0);   // v_pk_fma_f32
        acc1 = __builtin_elementwise_fma(wz1, ss1, acc1);
        acc2 = __builtin_elementwise_fma(wz2, ss2, acc2);
        acc3 = __builtin_elementwise_fma(wz3, ss3, acc3);
    }

    comb[wu][0][lane] = acc0;
    comb[wu][1][lane] = acc1;
    comb[wu][2][lane] = acc2;
    comb[wu][3][lane] = acc3;
    __syncthreads();

    if (wu < 4) {                                // wave wu finishes h = ht4*4+wu
        float na = 0.f, da = 0.f;
        #pragma unroll
        for (int js = 0; js < 8; ++js) {
            const v2f p = comb[js][wu][lane];
            na += p.x; da += p.y;
        }
        const int h = ht4 * 4 + wu;
        const int b = b0 + lane;
        const size_t hb = (size_t)h * LTC_B + b;
        if constexpr (MODE == 0) {
            o0[hb] = na;                         // snumT (coalesced)
            o1[hb] = da;                         // sdenT
        } else {
            const float gl = gleak[h], vl = vleak[h], c0 = cm[h];
            const float vpre = vT[hb];           // K==H here, coalesced
            const float num = fmaf(c0, vpre, gl * vl) + na + snumT[hb];
            const float den = c0 + gl + da + sdenT[hb];
            const float vn = num * __builtin_amdgcn_rcpf(den + 1e-8f);
            if constexpr (MODE == 1) o0[hb] = vn;            // next vT (KxB)
            else o0[(size_t)b * LTC_H + h] = vn;             // final B x H
        }
    }
}

extern "C" void kernel_launch(void* const* d_in, const int* in_sizes, int n_in,
                              void* d_out, int out_size, void* d_ws, size_t ws_size,
                              hipStream_t stream) {
    const float* inputs = (const float*)d_in[0];   // B x I
    const float* state  = (const float*)d_in[1];   // B x H
    const float* smu    = (const float*)d_in[2];   // I x H
    const float* ssig   = (const float*)d_in[3];
    const float* sW     = (const float*)d_in[4];
    const float* serev  = (const float*)d_in[5];
    const float* mu     = (const float*)d_in[6];   // H x H
    const float* sig    = (const float*)d_in[7];
    const float* W      = (const float*)d_in[8];
    const float* erev   = (const float*)d_in[9];
    const float* vleak  = (const float*)d_in[10];  // H
    const float* gleak  = (const float*)d_in[11];
    const float* cm     = (const float*)d_in[12];

    float* out = (float*)d_out;                    // B x H
    char*  ws  = (char*)d_ws;
    float*  snumT = (float*)(ws);                            // 1MB  H x B
    float*  sdenT = (float*)(ws + 1 * 1048576);              // 1MB  H x B
    float*  vTA   = (float*)(ws + 2 * 1048576);              // 1MB  H x B
    float*  vTB   = (float*)(ws + 3 * 1048576);              // 1MB  H x B
    float4* rslab = (float4*)(ws + 4 * 1048576);             // 4MB  [128][512][4]
    float4* sslab = (float4*)(ws + 8 * 1048576);             // 2MB  [128][256][4]
    float*  inpT  = (float*)(ws + 10 * 1048576);             // 0.5MB I x B

    // Weight transform (f32 quads, once per launch). One thread per (j,h).
    ltc_prep<LTC_H, 9><<<LTC_H * LTC_H / 256, 256, 0, stream>>>(mu, sig, W, erev, rslab);
    ltc_prep<LTC_I, 8><<<LTC_I * LTC_H / 256, 256, 0, stream>>>(smu, ssig, sW, serev, sslab);

    // Transpose activations into K x B layout.
    ltc_transpose<<<dim3(LTC_I / 64, LTC_B / 64), 256, 0, stream>>>(inputs, inpT, LTC_B, LTC_I);
    ltc_transpose<<<dim3(LTC_H / 64, LTC_B / 64), 256, 0, stream>>>(state, vTA, LTC_B, LTC_H);

    dim3 grid(LTC_H / 4, LTC_B / 64);              // (128 h-tiles, 8 b-cols)
    dim3 blk(512);

    // Sensory pass -> snumT/sdenT (H x B).
    ltc_pass<LTC_I, 0><<<grid, blk, 0, stream>>>(
        inpT, (const v2f*)sslab, nullptr, nullptr, nullptr, nullptr, nullptr,
        snumT, sdenT);

    // 6 unfolds: vTA -> vTB -> ... ; last writes B x H into d_out.
    const float* vin = vTA;
    float* vping[5] = {vTB, vTA, vTB, vTA, vTB};
    for (int s = 0; s < 5; ++s) {
        ltc_pass<LTC_H, 1><<<grid, blk, 0, stream>>>(
            vin, (const v2f*)rslab, snumT, sdenT, vleak, gleak, cm,
            vping[s], nullptr);
        vin = vping[s];
    }
    ltc_pass<LTC_H, 2><<<grid, blk, 0, stream>>>(
        vin, (const v2f*)rslab, snumT, sdenT, vleak, gleak, cm, out, nullptr);
}

// Round 10
// 292.278 us; speedup vs baseline: 1.3606x; 1.0388x over previous
//
#include <hip/hip_runtime.h>

#define LTC_B 512
#define LTC_H 512
#define LTC_I 256

static constexpr float kL2E = 1.4426950408889634f;  // log2(e)

typedef unsigned int u32;
#define AS_G __attribute__((address_space(1)))
#define AS_L __attribute__((address_space(3)))

__device__ __forceinline__ void ldg_lds16(const void* g, void* l) {
    // async global->LDS DMA, 16B/lane; LDS dest = wave-uniform base + lane*16
    __builtin_amdgcn_global_load_lds((const AS_G u32*)g, (AS_L u32*)l, 16, 0, 0);
}

// f32 weight quad per (j,h): a = -sigma*log2(e), ec = 2^(mu*sigma*log2(e)),
// wz = W*erev, wd = W.  sigma(b,j,h) = 1 / (1 + ec * 2^(a*v(b,j))).
// Quad index = (ht4*K + j)*4 + hh4, h = ht4*4 + hh4: a 16-j window of one
// ht4 is a contiguous 1KB run -> exactly one global_load_lds per window.
template<int K, int LOG2K>
__global__ void ltc_prep(const float* __restrict__ mu, const float* __restrict__ sigma,
                         const float* __restrict__ W, const float* __restrict__ erev,
                         float4* __restrict__ slab) {
    const int t = blockIdx.x * 256 + threadIdx.x;   // one thread per quad
    if (t >= K * LTC_H) return;
    const int hh4  = t & 3;
    const int rest = t >> 2;
    const int j    = rest & (K - 1);
    const int ht4  = rest >> LOG2K;
    const int h    = ht4 * 4 + hh4;
    const int g    = j * LTC_H + h;
    const float sg = sigma[g];
    float4 o;
    o.x = -sg * kL2E;                    // a
    o.y = exp2f(mu[g] * sg * kL2E);      // ec = 2^c
    o.z = W[g] * erev[g];                // wz
    o.w = W[g];                          // wd
    slab[t] = o;                         // coalesced 16B/lane
}

// Transpose B x C row-major -> v4 layout [C/4][B][4] (4 consecutive k packed
// per b so the pass kernel loads one float4 per 4 j). Verified in R6 run.
__global__ void ltc_transpose_v4(const float* __restrict__ in, float* __restrict__ out,
                                 int R, int C) {   // R = rows of in (= B)
    __shared__ float tile[64][65];
    const int bx = blockIdx.x * 64;      // col (k) base
    const int by = blockIdx.y * 64;      // row (b) base
    const int tx = threadIdx.x & 63;
    const int t4 = threadIdx.x >> 6;
    #pragma unroll
    for (int r = t4; r < 64; r += 4)
        tile[r][tx] = in[(size_t)(by + r) * C + bx + tx];
    __syncthreads();
    #pragma unroll
    for (int c = t4; c < 64; c += 4) {
        const int k = bx + c;
        out[((size_t)(k >> 2) * R + by + tx) * 4 + (k & 3)] = tile[tx][c];
    }
}

#define LTC_WAIT() asm volatile("s_waitcnt vmcnt(0) lgkmcnt(0)" ::: "memory")

// Lane = BATCH, per-wave DMA-ring weights (vmcnt-counted: no SMEM lgkmcnt(0)
// stall, no SGPR cap on prefetch depth). Block = 512 thr = 8 waves = 8
// j-slices for one (4-h tile, 64-b column). Per 16-j window: ONE
// global_load_lds (1KB) issued a full compute-window (~700+ cyc) ahead;
// weights consumed by broadcast ds_read_b128; v double-buffered in NAMED
// float4 registers (no arrays -> no scratch, R6's failure mode). w-loop
// fully unrolled via if constexpr -- all indices static. No loop barriers.
// MODE: 0 = sensory (write snumT/sdenT HxB), 1 = recurrent (write vT4),
//       2 = last recurrent (write out B x H).
template<int K, int MODE>
__global__ __launch_bounds__(512, 6)
void ltc_pass(const float4* __restrict__ vT4,    // [K/4][B][4]
              const float4* __restrict__ slab,   // [128][K][4]
              const float* __restrict__ snumT, const float* __restrict__ sdenT, // H x B
              const float* __restrict__ vleak, const float* __restrict__ gleak,
              const float* __restrict__ cm,
              float* __restrict__ o0, float* __restrict__ o1)
{
    constexpr int JW = K / 8;                    // j's per wave (64 / 32)
    constexpr int NW = JW / 16;                  // 16-j windows (4 / 2)

    __shared__ float4 wbuf[8][2][64];            // 16 KB: per-wave DMA ring
    __shared__ float2 comb[8][4][64];            // 16 KB: partials

    const int tid  = threadIdx.x;
    const int lane = tid & 63;
    const int wu   = __builtin_amdgcn_readfirstlane(tid >> 6);  // j-slice
    const int ht4  = blockIdx.x;                 // 0..127
    const int bc   = blockIdx.y * 64;            // b column base

    const char* sbase = (const char*)(slab + ((size_t)ht4 * K + (size_t)wu * JW) * 4);
    const float4* __restrict__ vp4 = vT4 + (size_t)(wu * (JW / 4)) * LTC_B + bc + lane;

    float na0 = 0.f, da0 = 0.f, na1 = 0.f, da1 = 0.f;
    float na2 = 0.f, da2 = 0.f, na3 = 0.f, da3 = 0.f;

    // one 16-j window from LDS buffer wq (wave-uniform -> broadcast ds_read),
    // v from 4 named float4 regs. R4-proven eval body (2-way rcp, plain fmac).
    auto window = [&](const float4* wq, const float4 u0, const float4 u1,
                      const float4 u2, const float4 u3) {
        #pragma unroll
        for (int jl = 0; jl < 16; ++jl) {
            const float4 uu = (jl >> 2) == 0 ? u0 : (jl >> 2) == 1 ? u1
                            : (jl >> 2) == 2 ? u2 : u3;
            const float vj = (jl & 3) == 0 ? uu.x : (jl & 3) == 1 ? uu.y
                           : (jl & 3) == 2 ? uu.z : uu.w;      // static after unroll
            const float4 q0 = wq[jl * 4 + 0];    // broadcast ds_read_b128
            const float4 q1 = wq[jl * 4 + 1];
            const float4 q2 = wq[jl * 4 + 2];
            const float4 q3 = wq[jl * 4 + 3];
            const float e0 = __builtin_amdgcn_exp2f(q0.x * vj);
            const float e1 = __builtin_amdgcn_exp2f(q1.x * vj);
            const float e2 = __builtin_amdgcn_exp2f(q2.x * vj);
            const float e3 = __builtin_amdgcn_exp2f(q3.x * vj);
            const float d0 = fmaf(q0.y, e0, 1.0f);
            const float d1 = fmaf(q1.y, e1, 1.0f);
            const float d2 = fmaf(q2.y, e2, 1.0f);
            const float d3 = fmaf(q3.y, e3, 1.0f);
            const float r01 = __builtin_amdgcn_rcpf(d0 * d1);   // 1 rcp / 2 sigmoids
            const float r23 = __builtin_amdgcn_rcpf(d2 * d3);
            const float s0 = r01 * d1, s1 = r01 * d0;
            const float s2 = r23 * d3, s3 = r23 * d2;
            na0 = fmaf(q0.z, s0, na0); da0 = fmaf(q0.w, s0, da0);
            na1 = fmaf(q1.z, s1, na1); da1 = fmaf(q1.w, s1, da1);
            na2 = fmaf(q2.z, s2, na2); da2 = fmaf(q2.w, s2, da2);
            na3 = fmaf(q3.z, s3, na3); da3 = fmaf(q3.w, s3, da3);
        }
    };

    // prologue: window 0 DMA + v in flight
    ldg_lds16(sbase + (size_t)lane * 16, &wbuf[wu][0][0]);
    float4 a0 = vp4[0 * LTC_B], a1 = vp4[1 * LTC_B],
           a2 = vp4[2 * LTC_B], a3 = vp4[3 * LTC_B];
    float4 e0, e1, e2, e3;                       // second v buffer (named)

    // w = 0
    LTC_WAIT();
    if constexpr (NW > 1) {
        ldg_lds16(sbase + 1024 + (size_t)lane * 16, &wbuf[wu][1][0]);
        e0 = vp4[4 * LTC_B]; e1 = vp4[5 * LTC_B];
        e2 = vp4[6 * LTC_B]; e3 = vp4[7 * LTC_B];
    }
    window(&wbuf[wu][0][0], a0, a1, a2, a3);
    // w = 1
    if constexpr (NW > 1) {
        LTC_WAIT();
        if constexpr (NW > 2) {
            ldg_lds16(sbase + 2048 + (size_t)lane * 16, &wbuf[wu][0][0]);
            a0 = vp4[8 * LTC_B];  a1 = vp4[9 * LTC_B];
            a2 = vp4[10 * LTC_B]; a3 = vp4[11 * LTC_B];
        }
        window(&wbuf[wu][1][0], e0, e1, e2, e3);
    }
    // w = 2
    if constexpr (NW > 2) {
        LTC_WAIT();
        ldg_lds16(sbase + 3072 + (size_t)lane * 16, &wbuf[wu][1][0]);
        e0 = vp4[12 * LTC_B]; e1 = vp4[13 * LTC_B];
        e2 = vp4[14 * LTC_B]; e3 = vp4[15 * LTC_B];
        window(&wbuf[wu][0][0], a0, a1, a2, a3);
    }
    // w = 3
    if constexpr (NW > 3) {
        LTC_WAIT();
        window(&wbuf[wu][1][0], e0, e1, e2, e3);
    }

    comb[wu][0][lane] = make_float2(na0, da0);
    comb[wu][1][lane] = make_float2(na1, da1);
    comb[wu][2][lane] = make_float2(na2, da2);
    comb[wu][3][lane] = make_float2(na3, da3);
    __syncthreads();

    if (wu < 4) {                                // wave wu finishes h = ht4*4+wu
        float na = 0.f, da = 0.f;
        #pragma unroll
        for (int js = 0; js < 8; ++js) {
            const float2 p = comb[js][wu][lane];
            na += p.x; da += p.y;
        }
        const int h = ht4 * 4 + wu;
        const int b = bc + lane;
        if constexpr (MODE == 0) {
            const size_t hb = (size_t)h * LTC_B + b;
            o0[hb] = na;                         // snumT (coalesced)
            o1[hb] = da;                         // sdenT
        } else {
            const size_t hb = (size_t)h * LTC_B + b;
            const size_t v4i = ((size_t)ht4 * LTC_B + b) * 4 + wu;  // vT4 slot of (h,b)
            const float gl = gleak[h], vl = vleak[h], c0 = cm[h];
            const float vpre = ((const float*)vT4)[v4i];            // K==H here
            const float num = fmaf(c0, vpre, gl * vl) + na + snumT[hb];
            const float den = c0 + gl + da + sdenT[hb];
            const float vn = num * __builtin_amdgcn_rcpf(den + 1e-8f);
            if constexpr (MODE == 1) o0[v4i] = vn;          // next vT4
            else o0[(size_t)b * LTC_H + h] = vn;            // final B x H
        }
    }
}

extern "C" void kernel_launch(void* const* d_in, const int* in_sizes, int n_in,
                              void* d_out, int out_size, void* d_ws, size_t ws_size,
                              hipStream_t stream) {
    const float* inputs = (const float*)d_in[0];   // B x I
    const float* state  = (const float*)d_in[1];   // B x H
    const float* smu    = (const float*)d_in[2];   // I x H
    const float* ssig   = (const float*)d_in[3];
    const float* sW     = (const float*)d_in[4];
    const float* serev  = (const float*)d_in[5];
    const float* mu     = (const float*)d_in[6];   // H x H
    const float* sig    = (const float*)d_in[7];
    const float* W      = (const float*)d_in[8];
    const float* erev   = (const float*)d_in[9];
    const float* vleak  = (const float*)d_in[10];  // H
    const float* gleak  = (const float*)d_in[11];
    const float* cm     = (const float*)d_in[12];

    float* out = (float*)d_out;                    // B x H
    char*  ws  = (char*)d_ws;
    float*  snumT = (float*)(ws);                            // 1MB  H x B
    float*  sdenT = (float*)(ws + 1 * 1048576);              // 1MB  H x B
    float4* vA    = (float4*)(ws + 2 * 1048576);             // 1MB  [H/4][B][4]
    float4* vB    = (float4*)(ws + 3 * 1048576);             // 1MB  [H/4][B][4]
    float4* rslab = (float4*)(ws + 4 * 1048576);             // 4MB  [128][512][4]
    float4* sslab = (float4*)(ws + 8 * 1048576);             // 2MB  [128][256][4]
    float4* inpT4 = (float4*)(ws + 10 * 1048576);            // 0.5MB [I/4][B][4]

    // Weight transform (f32 quads, once per launch). One thread per (j,h).
    ltc_prep<LTC_H, 9><<<LTC_H * LTC_H / 256, 256, 0, stream>>>(mu, sig, W, erev, rslab);
    ltc_prep<LTC_I, 8><<<LTC_I * LTC_H / 256, 256, 0, stream>>>(smu, ssig, sW, serev, sslab);

    // Activations into v4 layout.
    ltc_transpose_v4<<<dim3(LTC_I / 64, LTC_B / 64), 256, 0, stream>>>(inputs, (float*)inpT4, LTC_B, LTC_I);
    ltc_transpose_v4<<<dim3(LTC_H / 64, LTC_B / 64), 256, 0, stream>>>(state, (float*)vA, LTC_B, LTC_H);

    dim3 grid(LTC_H / 4, LTC_B / 64);              // (128 h-tiles, 8 b-cols) 2D
    dim3 blk(512);

    // Sensory pass -> snumT/sdenT (H x B).
    ltc_pass<LTC_I, 0><<<grid, blk, 0, stream>>>(
        inpT4, sslab, nullptr, nullptr, nullptr, nullptr, nullptr,
        snumT, sdenT);

    // 6 unfolds: vA -> vB -> ... ; last writes B x H into d_out.
    const float4* vin = vA;
    float4* vping[5] = {vB, vA, vB, vA, vB};
    for (int s = 0; s < 5; ++s) {
        ltc_pass<LTC_H, 1><<<grid, blk, 0, stream>>>(
            vin, rslab, snumT, sdenT, vleak, gleak, cm, (float*)vping[s], nullptr);
        vin = vping[s];
    }
    ltc_pass<LTC_H, 2><<<grid, blk, 0, stream>>>(
        vin, rslab, snumT, sdenT, vleak, gleak, cm, out, nullptr);
}